// Round 2
// baseline (125.903 us; speedup 1.0000x reference)
//
#include <hip/hip_runtime.h>
#include <math.h>

#define D_MODEL 512  // kernels assume D=512 (64 lanes x 8 floats)

__device__ __forceinline__ float dot8(const float4& a0, const float4& a1,
                                      const float4& b0, const float4& b1) {
    return a0.x * b0.x + a0.y * b0.y + a0.z * b0.z + a0.w * b0.w
         + a1.x * b1.x + a1.y * b1.y + a1.z * b1.z + a1.w * b1.w;
}

// Pass 1: online-softmax partial accumulation, 2 rows per iteration.
// One wave (64 lanes) handles one chunk of RPW consecutive rows of one batch.
// Lane i owns columns [4i,4i+4) and [256+4i,256+4i+4) -> coalesced float4 loads.
__global__ __launch_bounds__(256) void pool_pass1(
    const float* __restrict__ x, const float* __restrict__ w,
    float* __restrict__ acc_ws, float* __restrict__ ml_ws,
    int T, int C, int RPW)
{
    const int b    = blockIdx.y;
    const int wave = threadIdx.x >> 6;
    const int lane = threadIdx.x & 63;
    const int chunk = blockIdx.x * 4 + wave;
    if (chunk >= C) return;

    const float4 w0 = *(const float4*)(w + 4 * lane);
    const float4 w1 = *(const float4*)(w + 256 + 4 * lane);

    float  m = -INFINITY, l = 0.0f;
    float4 a0 = make_float4(0.f, 0.f, 0.f, 0.f);
    float4 a1 = make_float4(0.f, 0.f, 0.f, 0.f);

    const float* xr = x + (size_t)b * T * D_MODEL + (size_t)chunk * RPW * D_MODEL;
    for (int r = 0; r < RPW; r += 2, xr += 2 * D_MODEL) {
        // 4 independent 16B loads in flight
        const float4 u0 = *(const float4*)(xr + 4 * lane);
        const float4 u1 = *(const float4*)(xr + 256 + 4 * lane);
        const float4 v0 = *(const float4*)(xr + D_MODEL + 4 * lane);
        const float4 v1 = *(const float4*)(xr + D_MODEL + 256 + 4 * lane);

        float dp0 = dot8(u0, u1, w0, w1);
        float dp1 = dot8(v0, v1, w0, w1);
        #pragma unroll
        for (int off = 32; off >= 1; off >>= 1) {   // two interleaved chains
            dp0 += __shfl_xor(dp0, off);
            dp1 += __shfl_xor(dp1, off);
        }
        // block-of-2 online softmax update (bias dropped: shift-invariant)
        const float newm = fmaxf(m, fmaxf(dp0, dp1));
        if (newm > m) {                      // wave-uniform, rare (~log RPW)
            const float scale = __expf(m - newm);  // first hit: exp(-inf)=0, acc is 0
            l *= scale;
            a0.x *= scale; a0.y *= scale; a0.z *= scale; a0.w *= scale;
            a1.x *= scale; a1.y *= scale; a1.z *= scale; a1.w *= scale;
            m = newm;
        }
        const float p0 = __expf(dp0 - m);
        const float p1 = __expf(dp1 - m);
        l += p0 + p1;
        a0.x = fmaf(p0, u0.x, a0.x); a0.y = fmaf(p0, u0.y, a0.y);
        a0.z = fmaf(p0, u0.z, a0.z); a0.w = fmaf(p0, u0.w, a0.w);
        a1.x = fmaf(p0, u1.x, a1.x); a1.y = fmaf(p0, u1.y, a1.y);
        a1.z = fmaf(p0, u1.z, a1.z); a1.w = fmaf(p0, u1.w, a1.w);
        a0.x = fmaf(p1, v0.x, a0.x); a0.y = fmaf(p1, v0.y, a0.y);
        a0.z = fmaf(p1, v0.z, a0.z); a0.w = fmaf(p1, v0.w, a0.w);
        a1.x = fmaf(p1, v1.x, a1.x); a1.y = fmaf(p1, v1.y, a1.y);
        a1.z = fmaf(p1, v1.z, a1.z); a1.w = fmaf(p1, v1.w, a1.w);
    }

    float* accp = acc_ws + (size_t)(b * C + chunk) * D_MODEL;
    *(float4*)(accp + 4 * lane)       = a0;
    *(float4*)(accp + 256 + 4 * lane) = a1;
    if (lane == 0) {
        ml_ws[(b * C + chunk) * 2 + 0] = m;
        ml_ws[(b * C + chunk) * 2 + 1] = l;
    }
}

// Pass 2: combine chunk partials. grid=(B,4), block=256.
// Block (b,q): output columns [q*128, q*128+128). Thread = (cg=tid>>5, fx=tid&31):
// accumulates float4 at column q*128+fx*4 over chunks c = cg, cg+8, ...
__global__ __launch_bounds__(256) void pool_pass2(
    const float* __restrict__ acc_ws, const float* __restrict__ ml_ws,
    float* __restrict__ out, int C)
{
    const int b   = blockIdx.x;
    const int q   = blockIdx.y;
    const int tid = threadIdx.x;
    const int fx  = tid & 31;
    const int cg  = tid >> 5;

    __shared__ float  s_e[256];
    __shared__ float  red[256];
    __shared__ float4 s_acc[256];

    // block max of m over C chunks
    float mloc = -INFINITY;
    for (int c = tid; c < C; c += 256)
        mloc = fmaxf(mloc, ml_ws[(b * C + c) * 2 + 0]);
    red[tid] = mloc;
    __syncthreads();
    for (int s = 128; s > 0; s >>= 1) {
        if (tid < s) red[tid] = fmaxf(red[tid], red[tid + s]);
        __syncthreads();
    }
    const float M = red[0];
    __syncthreads();

    // per-chunk scale e_c = exp(m_c - M); L = sum e_c * l_c
    float lloc = 0.0f;
    for (int c = tid; c < C; c += 256) {
        const float e = __expf(ml_ws[(b * C + c) * 2 + 0] - M);
        s_e[c] = e;
        lloc += e * ml_ws[(b * C + c) * 2 + 1];
    }
    red[tid] = lloc;
    __syncthreads();
    for (int s = 128; s > 0; s >>= 1) {
        if (tid < s) red[tid] += red[tid + s];
        __syncthreads();
    }
    const float L = red[0];
    __syncthreads();

    // weighted sum of acc over chunks, 8-way parallel in c
    float4 sum = make_float4(0.f, 0.f, 0.f, 0.f);
    const float* base = acc_ws + (size_t)b * C * D_MODEL + q * 128 + fx * 4;
    for (int c = cg; c < C; c += 8) {
        const float  e = s_e[c];
        const float4 v = *(const float4*)(base + (size_t)c * D_MODEL);
        sum.x = fmaf(e, v.x, sum.x);
        sum.y = fmaf(e, v.y, sum.y);
        sum.z = fmaf(e, v.z, sum.z);
        sum.w = fmaf(e, v.w, sum.w);
    }
    s_acc[tid] = sum;
    __syncthreads();
    if (cg == 0) {
        float4 t = s_acc[fx];
        #pragma unroll
        for (int g = 1; g < 8; ++g) {
            const float4 o = s_acc[g * 32 + fx];
            t.x += o.x; t.y += o.y; t.z += o.z; t.w += o.w;
        }
        const float inv = 1.0f / L;
        float* op = out + b * D_MODEL + q * 128 + fx * 4;
        op[0] = t.x * inv; op[1] = t.y * inv; op[2] = t.z * inv; op[3] = t.w * inv;
    }
}

extern "C" void kernel_launch(void* const* d_in, const int* in_sizes, int n_in,
                              void* d_out, int out_size, void* d_ws, size_t ws_size,
                              hipStream_t stream)
{
    const float* x = (const float*)d_in[0];
    const float* w = (const float*)d_in[1];
    // d_in[2] (bias) intentionally ignored: softmax is shift-invariant.
    float* out = (float*)d_out;

    const int D = D_MODEL;
    const int B = 32;
    const int T = in_sizes[0] / (B * D);   // 8192

    // chunks per batch; shrink if workspace is small. Must divide T, multiple of 8.
    int C = 256;
    while (C > 8) {
        size_t need = (size_t)B * C * D * sizeof(float) + (size_t)B * C * 2 * sizeof(float);
        if (need <= ws_size) break;
        C >>= 1;
    }
    const int RPW = T / C;                 // 32 (even, required by 2-row unroll)

    float* acc_ws = (float*)d_ws;
    float* ml_ws  = acc_ws + (size_t)B * C * D;

    dim3 grid1(C / 4, B);
    pool_pass1<<<grid1, 256, 0, stream>>>(x, w, acc_ws, ml_ws, T, C, RPW);
    pool_pass2<<<dim3(B, 4), 256, 0, stream>>>(acc_ws, ml_ws, out, C);
}

// Round 3
// 116.376 us; speedup vs baseline: 1.0819x; 1.0819x over previous
//
#include <hip/hip_runtime.h>
#include <math.h>

#define D_MODEL 512  // kernels assume D=512 (64 lanes x 8 floats)

__device__ __forceinline__ float dot8(const float4& a0, const float4& a1,
                                      const float4& b0, const float4& b1) {
    return a0.x * b0.x + a0.y * b0.y + a0.z * b0.z + a0.w * b0.w
         + a1.x * b1.x + a1.y * b1.y + a1.z * b1.z + a1.w * b1.w;
}

// Pass 1: online-softmax partial accumulation, 4 rows per iteration.
// One wave (64 lanes) handles one chunk of RPW consecutive rows of one batch.
// Lane i owns columns [4i,4i+4) and [256+4i,256+4i+4) -> coalesced float4 loads.
__global__ __launch_bounds__(256) void pool_pass1(
    const float* __restrict__ x, const float* __restrict__ w,
    float* __restrict__ acc_ws, float* __restrict__ ml_ws,
    int T, int C, int RPW)
{
    const int b    = blockIdx.y;
    const int wave = threadIdx.x >> 6;
    const int lane = threadIdx.x & 63;
    const int chunk = blockIdx.x * 4 + wave;

    const float4 wa = *(const float4*)(w + 4 * lane);
    const float4 wb = *(const float4*)(w + 256 + 4 * lane);

    float  m = -INFINITY, l = 0.0f;
    float4 a0 = make_float4(0.f, 0.f, 0.f, 0.f);
    float4 a1 = make_float4(0.f, 0.f, 0.f, 0.f);

    const float* xr = x + (size_t)b * T * D_MODEL + (size_t)chunk * RPW * D_MODEL;
    for (int r = 0; r < RPW; r += 4, xr += 4 * D_MODEL) {
        // 8 independent 16B loads in flight
        const float4 r0a = *(const float4*)(xr                   + 4 * lane);
        const float4 r0b = *(const float4*)(xr             + 256 + 4 * lane);
        const float4 r1a = *(const float4*)(xr + 1*D_MODEL       + 4 * lane);
        const float4 r1b = *(const float4*)(xr + 1*D_MODEL + 256 + 4 * lane);
        const float4 r2a = *(const float4*)(xr + 2*D_MODEL       + 4 * lane);
        const float4 r2b = *(const float4*)(xr + 2*D_MODEL + 256 + 4 * lane);
        const float4 r3a = *(const float4*)(xr + 3*D_MODEL       + 4 * lane);
        const float4 r3b = *(const float4*)(xr + 3*D_MODEL + 256 + 4 * lane);

        float d0 = dot8(r0a, r0b, wa, wb);
        float d1 = dot8(r1a, r1b, wa, wb);
        float d2 = dot8(r2a, r2b, wa, wb);
        float d3 = dot8(r3a, r3b, wa, wb);
        #pragma unroll
        for (int off = 32; off >= 1; off >>= 1) {   // 4 interleaved chains
            d0 += __shfl_xor(d0, off);
            d1 += __shfl_xor(d1, off);
            d2 += __shfl_xor(d2, off);
            d3 += __shfl_xor(d3, off);
        }
        // block-of-4 online softmax update (bias dropped: shift-invariant)
        const float mx = fmaxf(fmaxf(d0, d1), fmaxf(d2, d3));
        if (mx > m) {                        // wave-uniform, rare (~log RPW)
            const float sc = __expf(m - mx); // first hit: exp(-inf)=0, acc is 0
            l *= sc;
            a0.x *= sc; a0.y *= sc; a0.z *= sc; a0.w *= sc;
            a1.x *= sc; a1.y *= sc; a1.z *= sc; a1.w *= sc;
            m = mx;
        }
        const float p0 = __expf(d0 - m);
        const float p1 = __expf(d1 - m);
        const float p2 = __expf(d2 - m);
        const float p3 = __expf(d3 - m);
        l += (p0 + p1) + (p2 + p3);
        a0.x = fmaf(p0, r0a.x, a0.x); a0.y = fmaf(p0, r0a.y, a0.y);
        a0.z = fmaf(p0, r0a.z, a0.z); a0.w = fmaf(p0, r0a.w, a0.w);
        a1.x = fmaf(p0, r0b.x, a1.x); a1.y = fmaf(p0, r0b.y, a1.y);
        a1.z = fmaf(p0, r0b.z, a1.z); a1.w = fmaf(p0, r0b.w, a1.w);
        a0.x = fmaf(p1, r1a.x, a0.x); a0.y = fmaf(p1, r1a.y, a0.y);
        a0.z = fmaf(p1, r1a.z, a0.z); a0.w = fmaf(p1, r1a.w, a0.w);
        a1.x = fmaf(p1, r1b.x, a1.x); a1.y = fmaf(p1, r1b.y, a1.y);
        a1.z = fmaf(p1, r1b.z, a1.z); a1.w = fmaf(p1, r1b.w, a1.w);
        a0.x = fmaf(p2, r2a.x, a0.x); a0.y = fmaf(p2, r2a.y, a0.y);
        a0.z = fmaf(p2, r2a.z, a0.z); a0.w = fmaf(p2, r2a.w, a0.w);
        a1.x = fmaf(p2, r2b.x, a1.x); a1.y = fmaf(p2, r2b.y, a1.y);
        a1.z = fmaf(p2, r2b.z, a1.z); a1.w = fmaf(p2, r2b.w, a1.w);
        a0.x = fmaf(p3, r3a.x, a0.x); a0.y = fmaf(p3, r3a.y, a0.y);
        a0.z = fmaf(p3, r3a.z, a0.z); a0.w = fmaf(p3, r3a.w, a0.w);
        a1.x = fmaf(p3, r3b.x, a1.x); a1.y = fmaf(p3, r3b.y, a1.y);
        a1.z = fmaf(p3, r3b.z, a1.z); a1.w = fmaf(p3, r3b.w, a1.w);
    }

    float* accp = acc_ws + (size_t)(b * C + chunk) * D_MODEL;
    *(float4*)(accp + 4 * lane)       = a0;
    *(float4*)(accp + 256 + 4 * lane) = a1;
    if (lane == 0) {
        ml_ws[(b * C + chunk) * 2 + 0] = m;
        ml_ws[(b * C + chunk) * 2 + 1] = l;
    }
}

// Pass 2: combine chunk partials. grid=(B,4), block=256.
// Block (b,q): output columns [q*128, q*128+128). Thread = (cg=tid>>5, fx=tid&31):
// accumulates float4 at column q*128+fx*4 over chunks c = cg, cg+8, ...
__global__ __launch_bounds__(256) void pool_pass2(
    const float* __restrict__ acc_ws, const float* __restrict__ ml_ws,
    float* __restrict__ out, int C)
{
    const int b   = blockIdx.x;
    const int q   = blockIdx.y;
    const int tid = threadIdx.x;
    const int fx  = tid & 31;
    const int cg  = tid >> 5;

    __shared__ float  s_e[256];
    __shared__ float  red[256];
    __shared__ float4 s_acc[256];

    // block max of m over C chunks
    float mloc = -INFINITY;
    for (int c = tid; c < C; c += 256)
        mloc = fmaxf(mloc, ml_ws[(b * C + c) * 2 + 0]);
    red[tid] = mloc;
    __syncthreads();
    for (int s = 128; s > 0; s >>= 1) {
        if (tid < s) red[tid] = fmaxf(red[tid], red[tid + s]);
        __syncthreads();
    }
    const float M = red[0];
    __syncthreads();

    // per-chunk scale e_c = exp(m_c - M); L = sum e_c * l_c
    float lloc = 0.0f;
    for (int c = tid; c < C; c += 256) {
        const float e = __expf(ml_ws[(b * C + c) * 2 + 0] - M);
        s_e[c] = e;
        lloc += e * ml_ws[(b * C + c) * 2 + 1];
    }
    red[tid] = lloc;
    __syncthreads();
    for (int s = 128; s > 0; s >>= 1) {
        if (tid < s) red[tid] += red[tid + s];
        __syncthreads();
    }
    const float L = red[0];
    __syncthreads();

    // weighted sum of acc over chunks, 8-way parallel in c
    float4 sum = make_float4(0.f, 0.f, 0.f, 0.f);
    const float* base = acc_ws + (size_t)b * C * D_MODEL + q * 128 + fx * 4;
    for (int c = cg; c < C; c += 8) {
        const float  e = s_e[c];
        const float4 v = *(const float4*)(base + (size_t)c * D_MODEL);
        sum.x = fmaf(e, v.x, sum.x);
        sum.y = fmaf(e, v.y, sum.y);
        sum.z = fmaf(e, v.z, sum.z);
        sum.w = fmaf(e, v.w, sum.w);
    }
    s_acc[tid] = sum;
    __syncthreads();
    if (cg == 0) {
        float4 t = s_acc[fx];
        #pragma unroll
        for (int g = 1; g < 8; ++g) {
            const float4 o = s_acc[g * 32 + fx];
            t.x += o.x; t.y += o.y; t.z += o.z; t.w += o.w;
        }
        const float inv = 1.0f / L;
        float* op = out + b * D_MODEL + q * 128 + fx * 4;
        op[0] = t.x * inv; op[1] = t.y * inv; op[2] = t.z * inv; op[3] = t.w * inv;
    }
}

extern "C" void kernel_launch(void* const* d_in, const int* in_sizes, int n_in,
                              void* d_out, int out_size, void* d_ws, size_t ws_size,
                              hipStream_t stream)
{
    const float* x = (const float*)d_in[0];
    const float* w = (const float*)d_in[1];
    // d_in[2] (bias) intentionally ignored: softmax is shift-invariant.
    float* out = (float*)d_out;

    const int D = D_MODEL;
    const int B = 32;
    const int T = in_sizes[0] / (B * D);   // 8192

    // chunks per batch; shrink if workspace is small. Must divide T, multiple of 4.
    int C = 128;
    while (C > 8) {
        size_t need = (size_t)B * C * D * sizeof(float) + (size_t)B * C * 2 * sizeof(float);
        if (need <= ws_size) break;
        C >>= 1;
    }
    const int RPW = T / C;                 // 64 (multiple of 4, required by unroll)

    float* acc_ws = (float*)d_ws;
    float* ml_ws  = acc_ws + (size_t)B * C * D;

    dim3 grid1(C / 4, B);
    pool_pass1<<<grid1, 256, 0, stream>>>(x, w, acc_ws, ml_ws, T, C, RPW);
    pool_pass2<<<dim3(B, 4), 256, 0, stream>>>(acc_ws, ml_ws, out, C);
}

// Round 5
// 101.862 us; speedup vs baseline: 1.2360x; 1.1425x over previous
//
#include <hip/hip_runtime.h>
#include <math.h>

#define D_MODEL 512  // kernels assume D=512 (64 lanes x 8 floats)

typedef float fx4 __attribute__((ext_vector_type(4)));

#define NTL(p) __builtin_nontemporal_load((const fx4*)(p))

__device__ __forceinline__ float dot8(const fx4& a0, const fx4& a1,
                                      const fx4& b0, const fx4& b1) {
    return a0.x * b0.x + a0.y * b0.y + a0.z * b0.z + a0.w * b0.w
         + a1.x * b1.x + a1.y * b1.y + a1.z * b1.z + a1.w * b1.w;
}

// Online-softmax update for a block of 4 rows held in registers.
__device__ __forceinline__ void process4(
    const fx4& r0a, const fx4& r0b, const fx4& r1a, const fx4& r1b,
    const fx4& r2a, const fx4& r2b, const fx4& r3a, const fx4& r3b,
    const fx4& wa, const fx4& wb,
    float& m, float& l, fx4& a0, fx4& a1)
{
    float d0 = dot8(r0a, r0b, wa, wb);
    float d1 = dot8(r1a, r1b, wa, wb);
    float d2 = dot8(r2a, r2b, wa, wb);
    float d3 = dot8(r3a, r3b, wa, wb);
    #pragma unroll
    for (int off = 32; off >= 1; off >>= 1) {   // 4 interleaved chains
        d0 += __shfl_xor(d0, off);
        d1 += __shfl_xor(d1, off);
        d2 += __shfl_xor(d2, off);
        d3 += __shfl_xor(d3, off);
    }
    const float mx = fmaxf(fmaxf(d0, d1), fmaxf(d2, d3));
    if (mx > m) {                        // wave-uniform, rare (~log RPW)
        const float sc = __expf(m - mx); // first hit: exp(-inf)=0, acc is 0
        l *= sc;
        a0 *= sc;
        a1 *= sc;
        m = mx;
    }
    const float p0 = __expf(d0 - m);
    const float p1 = __expf(d1 - m);
    const float p2 = __expf(d2 - m);
    const float p3 = __expf(d3 - m);
    l += (p0 + p1) + (p2 + p3);
    a0 += p0 * r0a; a1 += p0 * r0b;
    a0 += p1 * r1a; a1 += p1 * r1b;
    a0 += p2 * r2a; a1 += p2 * r2b;
    a0 += p3 * r3a; a1 += p3 * r3b;
}

// Pass 1: online-softmax partials, 4 rows/iter, software-pipelined one stage:
// iteration k+1's 8 nontemporal loads are issued BEFORE iteration k's
// shfl/exp/fma chain, so HBM latency hides under compute.
__global__ __launch_bounds__(256) void pool_pass1(
    const float* __restrict__ x, const float* __restrict__ w,
    float* __restrict__ acc_ws, float* __restrict__ ml_ws,
    int T, int C, int RPW)
{
    const int b    = blockIdx.y;
    const int wave = threadIdx.x >> 6;
    const int lane = threadIdx.x & 63;
    const int chunk = blockIdx.x * 4 + wave;

    const fx4 wa = *(const fx4*)(w + 4 * lane);
    const fx4 wb = *(const fx4*)(w + 256 + 4 * lane);

    float m = -INFINITY, l = 0.0f;
    fx4 a0 = (fx4)0.0f;
    fx4 a1 = (fx4)0.0f;

    const float* xr = x + (size_t)b * T * D_MODEL + (size_t)chunk * RPW * D_MODEL;

    // prologue: load rows 0..3
    fx4 c0a = NTL(xr                   + 4 * lane);
    fx4 c0b = NTL(xr             + 256 + 4 * lane);
    fx4 c1a = NTL(xr + 1*D_MODEL       + 4 * lane);
    fx4 c1b = NTL(xr + 1*D_MODEL + 256 + 4 * lane);
    fx4 c2a = NTL(xr + 2*D_MODEL       + 4 * lane);
    fx4 c2b = NTL(xr + 2*D_MODEL + 256 + 4 * lane);
    fx4 c3a = NTL(xr + 3*D_MODEL       + 4 * lane);
    fx4 c3b = NTL(xr + 3*D_MODEL + 256 + 4 * lane);

    for (int r = 0; r < RPW - 4; r += 4) {
        xr += 4 * D_MODEL;
        // issue next block's loads first (independent registers)
        const fx4 n0a = NTL(xr                   + 4 * lane);
        const fx4 n0b = NTL(xr             + 256 + 4 * lane);
        const fx4 n1a = NTL(xr + 1*D_MODEL       + 4 * lane);
        const fx4 n1b = NTL(xr + 1*D_MODEL + 256 + 4 * lane);
        const fx4 n2a = NTL(xr + 2*D_MODEL       + 4 * lane);
        const fx4 n2b = NTL(xr + 2*D_MODEL + 256 + 4 * lane);
        const fx4 n3a = NTL(xr + 3*D_MODEL       + 4 * lane);
        const fx4 n3b = NTL(xr + 3*D_MODEL + 256 + 4 * lane);

        process4(c0a, c0b, c1a, c1b, c2a, c2b, c3a, c3b, wa, wb, m, l, a0, a1);

        c0a = n0a; c0b = n0b; c1a = n1a; c1b = n1b;   // register rotate
        c2a = n2a; c2b = n2b; c3a = n3a; c3b = n3b;   // (renamed by compiler)
    }
    process4(c0a, c0b, c1a, c1b, c2a, c2b, c3a, c3b, wa, wb, m, l, a0, a1);

    float* accp = acc_ws + (size_t)(b * C + chunk) * D_MODEL;
    *(fx4*)(accp + 4 * lane)       = a0;
    *(fx4*)(accp + 256 + 4 * lane) = a1;
    if (lane == 0) {
        ml_ws[(b * C + chunk) * 2 + 0] = m;
        ml_ws[(b * C + chunk) * 2 + 1] = l;
    }
}

// Pass 2: combine chunk partials. grid=(B,4), block=256.
__global__ __launch_bounds__(256) void pool_pass2(
    const float* __restrict__ acc_ws, const float* __restrict__ ml_ws,
    float* __restrict__ out, int C)
{
    const int b   = blockIdx.x;
    const int q   = blockIdx.y;
    const int tid = threadIdx.x;
    const int fx  = tid & 31;
    const int cg  = tid >> 5;

    __shared__ float s_e[256];
    __shared__ float red[256];
    __shared__ fx4   s_acc[256];

    float mloc = -INFINITY;
    for (int c = tid; c < C; c += 256)
        mloc = fmaxf(mloc, ml_ws[(b * C + c) * 2 + 0]);
    red[tid] = mloc;
    __syncthreads();
    for (int s = 128; s > 0; s >>= 1) {
        if (tid < s) red[tid] = fmaxf(red[tid], red[tid + s]);
        __syncthreads();
    }
    const float M = red[0];
    __syncthreads();

    float lloc = 0.0f;
    for (int c = tid; c < C; c += 256) {
        const float e = __expf(ml_ws[(b * C + c) * 2 + 0] - M);
        s_e[c] = e;
        lloc += e * ml_ws[(b * C + c) * 2 + 1];
    }
    red[tid] = lloc;
    __syncthreads();
    for (int s = 128; s > 0; s >>= 1) {
        if (tid < s) red[tid] += red[tid + s];
        __syncthreads();
    }
    const float L = red[0];
    __syncthreads();

    fx4 sum = (fx4)0.0f;
    const float* base = acc_ws + (size_t)b * C * D_MODEL + q * 128 + fx * 4;
    for (int c = cg; c < C; c += 8) {
        sum += s_e[c] * *(const fx4*)(base + (size_t)c * D_MODEL);
    }
    s_acc[tid] = sum;
    __syncthreads();
    if (cg == 0) {
        fx4 t = s_acc[fx];
        #pragma unroll
        for (int g = 1; g < 8; ++g) t += s_acc[g * 32 + fx];
        const float inv = 1.0f / L;
        t *= inv;
        float* op = out + b * D_MODEL + q * 128 + fx * 4;
        *(fx4*)op = t;
    }
}

extern "C" void kernel_launch(void* const* d_in, const int* in_sizes, int n_in,
                              void* d_out, int out_size, void* d_ws, size_t ws_size,
                              hipStream_t stream)
{
    const float* x = (const float*)d_in[0];
    const float* w = (const float*)d_in[1];
    // d_in[2] (bias) intentionally ignored: softmax is shift-invariant.
    float* out = (float*)d_out;

    const int D = D_MODEL;
    const int B = 32;
    const int T = in_sizes[0] / (B * D);   // 8192

    int C = 128;
    while (C > 8) {
        size_t need = (size_t)B * C * D * sizeof(float) + (size_t)B * C * 2 * sizeof(float);
        if (need <= ws_size) break;
        C >>= 1;
    }
    const int RPW = T / C;                 // 64 (multiple of 4, >= 8)

    float* acc_ws = (float*)d_ws;
    float* ml_ws  = acc_ws + (size_t)B * C * D;

    dim3 grid1(C / 4, B);
    pool_pass1<<<grid1, 256, 0, stream>>>(x, w, acc_ws, ml_ws, T, C, RPW);
    pool_pass2<<<dim3(B, 4), 256, 0, stream>>>(acc_ws, ml_ws, out, C);
}